// Round 1
// baseline (1168.397 us; speedup 1.0000x reference)
//
#include <hip/hip_runtime.h>

// OctreeMaxUnpool: out[i*8 + c, k] = (indices[i,k] == c) ? data[nempty_idx[i], k] : 0
// num = 500000, C = 64. Output [num*8, 64] fp32 = 1.024 GB -> write-bound.
//
// R4 (this session R0): A/B the store path. R3 used __builtin_nontemporal_store
// for all 8 child stores and measured 1182 µs ≈ 1.08 TB/s effective — ~4-6x off
// the ~205 µs roofline. That gap matches 4x write amplification (each 16B nt
// store costing a 64B line). This round: REGULAR stores (write-back through L2,
// which guarantees full-line merging: the 4 16B stores per 64B line are issued
// back-to-back within one wave-instruction). Keep nt on the indices load
// (streamed exactly once). Everything else identical to the verified R3.

typedef float vfloat4 __attribute__((ext_vector_type(4)));
typedef int   vint4   __attribute__((ext_vector_type(4)));

constexpr int C4 = 16;      // float4s per row (C=64)
constexpr int NCHILD = 8;

__global__ __launch_bounds__(256) void octree_unpool_kernel(
    const vfloat4* __restrict__ data,      // [N, 16] as float4
    const vint4*   __restrict__ indices,   // [num, 16] as int4
    const int*     __restrict__ nempty,    // [num]
    vfloat4*       __restrict__ out,       // [num*8, 16] as float4
    int num)
{
    int t = blockIdx.x * blockDim.x + threadIdx.x;
    int total = num * C4;                 // 8M threads
    if (t >= total) return;

    int i  = t >> 4;        // octant group
    int k4 = t & 15;        // float4 chunk within row

    int row = nempty[i];    // 16 threads share -> 4 distinct addrs/wave

    vint4   idx4 = __builtin_nontemporal_load(&indices[i * C4 + k4]);
    // 32-bit index: row < 600000 -> row*16+k4 < 9.6M float4, fits easily.
    vfloat4 d4   = data[row * C4 + k4];

    vfloat4* base = out + (long long)i * (NCHILD * C4) + k4;

#pragma unroll
    for (int c = 0; c < NCHILD; ++c) {
        vfloat4 o;
        o.x = (idx4.x == c) ? d4.x : 0.0f;
        o.y = (idx4.y == c) ? d4.y : 0.0f;
        o.z = (idx4.z == c) ? d4.z : 0.0f;
        o.w = (idx4.w == c) ? d4.w : 0.0f;
        base[c * C4] = o;   // regular store: write-back L2 merges full lines
    }
}

extern "C" void kernel_launch(void* const* d_in, const int* in_sizes, int n_in,
                              void* d_out, int out_size, void* d_ws, size_t ws_size,
                              hipStream_t stream) {
    const vfloat4* data    = (const vfloat4*)d_in[0];
    const vint4*   indices = (const vint4*)  d_in[1];
    const int*     nempty  = (const int*)    d_in[2];
    // d_in[3] = depth (unused)
    vfloat4* out = (vfloat4*)d_out;

    int num = in_sizes[2];                 // 500000
    int total = num * C4;                  // one thread per (i, k4)
    int block = 256;
    int grid = (total + block - 1) / block;

    octree_unpool_kernel<<<grid, block, 0, stream>>>(data, indices, nempty, out, num);
}

// Round 2
// 1160.223 us; speedup vs baseline: 1.0070x; 1.0070x over previous
//
#include <hip/hip_runtime.h>

// OctreeMaxUnpool: out[i*8 + c, k] = (indices[i,k] == c) ? data[nempty_idx[i], k] : 0
// num = 500000, C = 64. Output 1.024 GB. Ideal traffic ~1.28 GB -> ~205 us @ 6.3 TB/s.
//
// R5 MEASUREMENT PROBE (deliberate): the rocprof top-5 is fully masked by the
// harness's 650-us / 4.096-GB re-poison fills, so our kernel's counters are
// invisible and dur_us (1168) is fill + harness resets + kernel. This version
// executes the body TWICE (second pass stores identical values; memory barrier
// prevents store merging). Outcomes:
//   (A) kernel was ~515 us -> doubled kernel (~1030 us) becomes top-1 dispatch
//       WITH counters (WRITE_SIZE tells us the amplification factor directly).
//   (B) kernel was ~215 us (roofline) -> stays hidden, dur rises by only
//       ~215-250 us -> declare roofline next round.
// Correctness is unchanged: pass 2 rewrites the same values.

typedef float vfloat4 __attribute__((ext_vector_type(4)));
typedef int   vint4   __attribute__((ext_vector_type(4)));

constexpr int C4 = 16;      // float4s per row (C=64)
constexpr int NCHILD = 8;

__global__ __launch_bounds__(256) void octree_unpool_kernel(
    const vfloat4* __restrict__ data,      // [N, 16] as float4
    const vint4*   __restrict__ indices,   // [num, 16] as int4
    const int*     __restrict__ nempty,    // [num]
    vfloat4*       __restrict__ out,       // [num*8, 16] as float4
    int num)
{
    int t = blockIdx.x * blockDim.x + threadIdx.x;
    int total = num * C4;                 // 8M threads
    if (t >= total) return;

    int i  = t >> 4;        // octant group
    int k4 = t & 15;        // float4 chunk within row

#pragma unroll 1
    for (int rep = 0; rep < 2; ++rep) {
        int row = nempty[i];    // 16 threads share -> 4 distinct addrs/wave

        vint4   idx4 = __builtin_nontemporal_load(&indices[i * C4 + k4]);
        vfloat4 d4   = data[row * C4 + k4];

        vfloat4* base = out + (long long)i * (NCHILD * C4) + k4;

#pragma unroll
        for (int c = 0; c < NCHILD; ++c) {
            vfloat4 o;
            o.x = (idx4.x == c) ? d4.x : 0.0f;
            o.y = (idx4.y == c) ? d4.y : 0.0f;
            o.z = (idx4.z == c) ? d4.z : 0.0f;
            o.w = (idx4.w == c) ? d4.w : 0.0f;
            base[c * C4] = o;   // full-line-covered streaming store
        }
        // Compiler-level full barrier: pass-2 loads/stores cannot be merged
        // with pass-1 (global stores are not dead, loads must re-issue).
        asm volatile("" ::: "memory");
    }
}

extern "C" void kernel_launch(void* const* d_in, const int* in_sizes, int n_in,
                              void* d_out, int out_size, void* d_ws, size_t ws_size,
                              hipStream_t stream) {
    const vfloat4* data    = (const vfloat4*)d_in[0];
    const vint4*   indices = (const vint4*)  d_in[1];
    const int*     nempty  = (const int*)    d_in[2];
    // d_in[3] = depth (unused)
    vfloat4* out = (vfloat4*)d_out;

    int num = in_sizes[2];                 // 500000
    int total = num * C4;                  // one thread per (i, k4)
    int block = 256;
    int grid = (total + block - 1) / block;

    octree_unpool_kernel<<<grid, block, 0, stream>>>(data, indices, nempty, out, num);
}